// Round 3
// baseline (303.817 us; speedup 1.0000x reference)
//
#include <hip/hip_runtime.h>
#include <hip/hip_fp16.h>

#define PCELLS (16*16*16*16*16)   // 1048576
#define CCH 32
#define TILE_P 128

typedef float f32x4 __attribute__((ext_vector_type(4)));

// xor-4 lane butterfly via ds_swizzle (BitMode: xor=4, and=0x1F -> 0x101F)
__device__ __forceinline__ float swz_xor4(float x) {
    return __int_as_float(__builtin_amdgcn_ds_swizzle(__float_as_int(x), 0x101F));
}

// ---------------------------------------------------------------------------
// K1: (C=32, P) f32 -> permuted (cell, C=32) f16,  cell = r*256 + d0*16 + d1.
// Original p = (d0*16+d1)*4096 + r, so a 128-p tile has fixed d01 and
// contiguous r. Reads coalesced nontemporal float4; stores nontemporal
// (table is consumed by the next kernel through L2 anyway; 64 MiB >> L2).
// ---------------------------------------------------------------------------
__global__ __launch_bounds__(256) void transpose_kernel(
        const float* __restrict__ g, __half* __restrict__ gt) {
    __shared__ float tile[CCH][TILE_P + 4];
    const int p0  = blockIdx.x * TILE_P;
    const int d01 = blockIdx.x >> 5;              // d0*16 + d1
    const int rb  = (blockIdx.x & 31) * TILE_P;   // r base (0..4095)
    const int t   = threadIdx.x;

#pragma unroll
    for (int i = 0; i < 4; ++i) {
        int idx = t + i * 256;
        int c   = idx >> 5;
        int q   = idx & 31;
        const f32x4 v = __builtin_nontemporal_load(
            (const f32x4*)(g + (size_t)c * PCELLS + p0 + 4 * q));
        *(f32x4*)&tile[c][4 * q] = v;
    }
    __syncthreads();

#pragma unroll
    for (int i = 0; i < 2; ++i) {
        int idx = t + i * 256;
        int p   = idx >> 2;
        int k   = idx & 3;
        __half2 h[4];
#pragma unroll
        for (int j = 0; j < 4; ++j)
            h[j] = __floats2half2_rn(tile[8 * k + 2 * j][p],
                                     tile[8 * k + 2 * j + 1][p]);
        size_t cell = (size_t)(rb + p) * 256 + d01;
        __builtin_nontemporal_store(*(f32x4*)h,
                                    (f32x4*)(gt + cell * CCH + 8 * k));
    }
}

// ---------------------------------------------------------------------------
// K2: fused prep+gather. 8 lanes per ray, FOUR rays per thread (wave = 32
// rays) -> 8 independent 16 B gathers in flight per thread. Cooperative ray
// read: lane j loads only dim min(j,4) of each ray (1 dword), scales it with
// its own mn/mx (2 scalar loads/thread total), broadcasts the scaled index
// with ds_bpermute (LDS pipe idle). Per ray only TWO scattered 128 B spans
// (corner pairs (l,l+1) and (l+16,l+17)); lane j covers bytes 16j of the
// span -> cell l + (j>>2), channel octet j&3. The d1-corner pair is combined
// with one xor-4 lane butterfly per accumulator float; each wave's stores
// cover contiguous 1 KiB output rows.
// ---------------------------------------------------------------------------
__global__ __launch_bounds__(256) void fused_gather(
        const float* __restrict__ ray, const __half* __restrict__ gt,
        const float* __restrict__ mn, const float* __restrict__ mx,
        float* __restrict__ out, int N) {
    int tid  = blockIdx.x * blockDim.x + threadIdx.x;
    int lane = tid & 63;
    int wv   = tid >> 6;          // global wave id
    int gi   = lane >> 3;         // group within wave (8 lanes/group)
    int j    = lane & 7;          // lane within group
    long long base = (long long)wv * 32;
    if (base >= N) return;        // wave-uniform exit (bpermute-safe)

    const int jd = j < 5 ? j : 4; // this lane's ray dimension
    float m_d   = mn[jd];
    float inv_d = __builtin_amdgcn_rcpf(mx[jd] - m_d) * 15.0f;

    // --- ray indices (group gi owns rays base + 8r + gi, r = 0..3) ---------
    int n[4]; bool has[4];
#pragma unroll
    for (int r = 0; r < 4; ++r) {
        int nr = (int)base + r * 8 + gi;
        has[r] = nr < N;
        n[r]   = has[r] ? nr : (N - 1);
    }

    // --- cooperative load + scale + broadcast of grid-space indices --------
    float x[4][5];
#pragma unroll
    for (int r = 0; r < 4; ++r) {
        float rv = ray[(size_t)n[r] * 5 + jd];
        int xi = __float_as_int((rv - m_d) * inv_d);
#pragma unroll
        for (int d = 0; d < 5; ++d)
            x[r][d] = __int_as_float(
                __builtin_amdgcn_ds_bpermute(4 * (gi * 8 + d), xi));
    }

    // --- per-ray corner base + folded weights ------------------------------
    const int h = j >> 2;         // d1-corner this lane holds
    int   l[4];
    float cA[4], cB[4];
#pragma unroll
    for (int r = 0; r < 4; ++r) {
        float w[5]; int b[5];
#pragma unroll
        for (int d = 0; d < 5; ++d) {
            float f = floorf(x[r][d]);
            b[d] = (int)f;
            w[d] = x[r][d] - f;
        }
        float tau = (1.f - w[2]) * (1.f - w[3]) * (1.f - w[4]);
        int lr = (b[2] * 256 + b[3] * 16 + b[4]) * 256 + b[0] * 16 + b[1];
        l[r] = min(max(lr, 0), PCELLS - 18);
        float f1 = h ? w[1] : 1.f - w[1];
        cA[r] = (1.f - w[0]) * tau * f1;   // d0 bottom
        cB[r] = w[0] * tau * f1;           // d0+1
    }

    // --- issue all 8 gathers -----------------------------------------------
    const char* gb = (const char*)gt;
    const size_t off = (size_t)16 * j;
    f32x4 vA[4], vB[4];
#pragma unroll
    for (int r = 0; r < 4; ++r) {
        vA[r] = *(const f32x4*)(gb + (size_t)l[r] * 64 + off);        // (l, l+1)
        vB[r] = *(const f32x4*)(gb + (size_t)(l[r] + 16) * 64 + off); // (l+16, l+17)
    }

    // --- accumulate, combine d1 corners across the xor-4 pair, store -------
    const int qo = j & 3;
#pragma unroll
    for (int r = 0; r < 4; ++r) {
        float acc[8];
        const __half2* hA = (const __half2*)&vA[r];
        const __half2* hB = (const __half2*)&vB[r];
#pragma unroll
        for (int k = 0; k < 4; ++k) {
            float2 a = __half22float2(hA[k]);
            float2 bvl = __half22float2(hB[k]);
            acc[2 * k]     = cA[r] * a.x + cB[r] * bvl.x;
            acc[2 * k + 1] = cA[r] * a.y + cB[r] * bvl.y;
        }
#pragma unroll
        for (int k = 0; k < 8; ++k)
            acc[k] += swz_xor4(acc[k]);

        if (has[r]) {
            f32x4 lo = *(f32x4*)&acc[0], hi = *(f32x4*)&acc[4];
            f32x4 st = h ? hi : lo;
            __builtin_nontemporal_store(
                st, (f32x4*)(out + (size_t)n[r] * CCH + 8 * qo + 4 * h));
        }
    }
}

// ---------------------------------------------------------------------------
// Fallback: direct gather from native (C,P) f32 layout (workspace too small).
// ---------------------------------------------------------------------------
__device__ __forceinline__ void ray_corners_orig(
        const float* __restrict__ ray, const float* __restrict__ mn,
        const float* __restrict__ mx, int n, int* lin, float* wt) {
    float w[5]; int b[5];
#pragma unroll
    for (int d = 0; d < 5; ++d) {
        float m   = mn[d];
        float inv = __builtin_amdgcn_rcpf(mx[d] - m) * 15.0f;
        float i0  = (ray[(size_t)n * 5 + d] - m) * inv;
        float f0  = floorf(i0);
        b[d] = (int)f0;  w[d] = i0 - f0;
    }
    float tau = (1.f - w[2]) * (1.f - w[3]) * (1.f - w[4]);
    int rest  = b[2] * 256 + b[3] * 16 + b[4];
    wt[0] = (1.f - w[0]) * (1.f - w[1]) * tau;
    wt[1] = w[0] * (1.f - w[1]) * tau;
    wt[2] = (1.f - w[0]) * w[1] * tau;
    wt[3] = w[0] * w[1] * tau;
    int l00 = b[0] * 65536 + b[1] * 4096 + rest;
    int lv[4] = { l00, l00 + 65536, l00 + 4096, l00 + 65536 + 4096 };
#pragma unroll
    for (int f = 0; f < 4; ++f)
        lin[f] = min(max(lv[f], 0), PCELLS - 1);
}

__global__ __launch_bounds__(256) void direct_kernel(
        const float* __restrict__ ray, const float* __restrict__ g,
        const float* __restrict__ mn, const float* __restrict__ mx,
        float* __restrict__ out, int N) {
    int tid = blockIdx.x * blockDim.x + threadIdx.x;
    int n = tid >> 5;
    int c = tid & 31;
    if (n >= N) return;
    int lin[4]; float wt[4];
    ray_corners_orig(ray, mn, mx, n, lin, wt);
    const float* gc = g + (size_t)c * PCELLS;
    float acc = wt[0] * gc[lin[0]] + wt[1] * gc[lin[1]] +
                wt[2] * gc[lin[2]] + wt[3] * gc[lin[3]];
    out[(size_t)n * CCH + c] = acc;
}

extern "C" void kernel_launch(void* const* d_in, const int* in_sizes, int n_in,
                              void* d_out, int out_size, void* d_ws, size_t ws_size,
                              hipStream_t stream) {
    const float* ray  = (const float*)d_in[0];
    const float* grid = (const float*)d_in[1];
    const float* mn   = (const float*)d_in[2];
    const float* mx   = (const float*)d_in[3];
    float* out = (float*)d_out;
    const int N = in_sizes[0] / 5;

    const size_t gt_bytes = (size_t)PCELLS * CCH * sizeof(__half);   // 64 MiB

    if (ws_size >= gt_bytes) {
        __half* gt = (__half*)d_ws;
        transpose_kernel<<<PCELLS / TILE_P, 256, 0, stream>>>(grid, gt);

        long long waves   = ((long long)N + 31) / 32;   // 32 rays per wave
        long long threads = waves * 64;
        fused_gather<<<(int)((threads + 255) / 256), 256, 0, stream>>>(
            ray, gt, mn, mx, out, N);
    } else {
        long long total = (long long)N * CCH;
        direct_kernel<<<(int)((total + 255) / 256), 256, 0, stream>>>(
            ray, grid, mn, mx, out, N);
    }
}

// Round 4
// 298.973 us; speedup vs baseline: 1.0162x; 1.0162x over previous
//
#include <hip/hip_runtime.h>
#include <hip/hip_fp16.h>

#define PCELLS (16*16*16*16*16)   // 1048576
#define CCH 32

typedef float f32x4 __attribute__((ext_vector_type(4)));
// 4-B-aligned float4 (ray rows are 20 B apart; CDNA supports unaligned VMEM)
typedef float f32x4u __attribute__((ext_vector_type(4), aligned(4)));

// xor-4 lane butterfly via ds_swizzle (BitMode: xor=4, and=0x1F -> 0x101F)
__device__ __forceinline__ float swz_xor4(float x) {
    return __int_as_float(__builtin_amdgcn_ds_swizzle(__float_as_int(x), 0x101F));
}

// ---------------------------------------------------------------------------
// K1: (C=32, P) f32 -> permuted (cell, C=32) f16,  cell = r*256 + d0*16 + d1.
// Original p = (d0*16+d1)*4096 + r. Each block handles a d01 PAIR x 64 r, so
// each 8-lane store group writes two adjacent cells = contiguous 128 B
// (was 64-B segments). Reads stay coalesced nontemporal float4.
// ---------------------------------------------------------------------------
__global__ __launch_bounds__(256) void transpose_kernel(
        const float* __restrict__ g, __half* __restrict__ gt) {
    __shared__ float tile[CCH][2][65];            // [c][d01h][r], pad 1
    const int d01b = (blockIdx.x >> 6) * 2;       // 0,2,...,254
    const int r0   = (blockIdx.x & 63) * 64;      // r tile base
    const int t    = threadIdx.x;

    // load 32c x 2d01 x 64r = 16 KB, 4 iters x 256 thr x 16 B
#pragma unroll
    for (int i = 0; i < 4; ++i) {
        int idx = t + i * 256;            // 0..1023
        int c   = idx >> 5;
        int dh  = (idx >> 4) & 1;
        int q   = idx & 15;
        const f32x4 v = __builtin_nontemporal_load(
            (const f32x4*)(g + (size_t)c * PCELLS + (size_t)(d01b + dh) * 4096
                             + r0 + 4 * q));
        *(f32x4*)&tile[c][dh][4 * q] = v;
    }
    __syncthreads();

    // store 64r x 2d01 x 64 B = 512 units of 16 B, 2 iters
#pragma unroll
    for (int i = 0; i < 2; ++i) {
        int idx = t + i * 256;            // 0..511
        int r   = idx >> 3;
        int dh  = (idx >> 2) & 1;
        int k   = idx & 3;
        __half2 h[4];
#pragma unroll
        for (int jj = 0; jj < 4; ++jj)
            h[jj] = __floats2half2_rn(tile[8 * k + 2 * jj][dh][r],
                                      tile[8 * k + 2 * jj + 1][dh][r]);
        size_t cell = (size_t)(r0 + r) * 256 + d01b + dh;
        __builtin_nontemporal_store(*(f32x4*)h,
                                    (f32x4*)(gt + cell * CCH + 8 * k));
    }
}

// ---------------------------------------------------------------------------
// K2: fused prep+gather (round-2 structure: 8 lanes/ray, 2 rays/thread,
// wave = 16 rays). Per ray TWO scattered 128-B spans (corner pairs (l,l+1),
// (l+16,l+17)); lane j covers bytes 16j -> cell l+(j>>2), channel octet j&3.
// d1-corner pair combined with one xor-4 butterfly per accumulator float.
// Ray loads vectorized: dwordx4 + dword per ray (4-B aligned OK on CDNA).
// ---------------------------------------------------------------------------
__global__ __launch_bounds__(256) void fused_gather(
        const float* __restrict__ ray, const __half* __restrict__ gt,
        const float* __restrict__ mn, const float* __restrict__ mx,
        float* __restrict__ out, int N) {
    int tid  = blockIdx.x * blockDim.x + threadIdx.x;
    int lane = tid & 63;
    int wv   = tid >> 6;          // global wave id
    int gi   = lane >> 3;         // group within wave (8 lanes/group)
    int j    = lane & 7;          // lane within group
    int n0   = wv * 16 + gi;      // wave handles rays [16w, 16w+16)
    if (n0 >= N) return;          // group-uniform exit
    int  n1   = n0 + 8;
    bool has1 = n1 < N;
    int  n1c  = has1 ? n1 : n0;

    // --- vectorized ray loads ---------------------------------------------
    const float* rp0 = ray + (size_t)n0  * 5;
    const float* rp1 = ray + (size_t)n1c * 5;
    float rv0[5], rv1[5];
    *(f32x4u*)rv0 = *(const f32x4u*)rp0;  rv0[4] = rp0[4];
    *(f32x4u*)rv1 = *(const f32x4u*)rp1;  rv1[4] = rp1[4];

    // --- corner base + weights --------------------------------------------
    float wa[5], wb[5]; int ba[5], bb[5];
#pragma unroll
    for (int d = 0; d < 5; ++d) {
        float m   = mn[d];
        float inv = __builtin_amdgcn_rcpf(mx[d] - m) * 15.0f;
        float i0  = (rv0[d] - m) * inv;
        float i1  = (rv1[d] - m) * inv;
        float f0 = floorf(i0), f1 = floorf(i1);
        ba[d] = (int)f0;  wa[d] = i0 - f0;
        bb[d] = (int)f1;  wb[d] = i1 - f1;
    }
    float ta = (1.f - wa[2]) * (1.f - wa[3]) * (1.f - wa[4]);
    float tb = (1.f - wb[2]) * (1.f - wb[3]) * (1.f - wb[4]);
    int la = (ba[2] * 256 + ba[3] * 16 + ba[4]) * 256 + ba[0] * 16 + ba[1];
    int lb = (bb[2] * 256 + bb[3] * 16 + bb[4]) * 256 + bb[0] * 16 + bb[1];
    int l0 = min(max(la, 0), PCELLS - 18);
    int l1 = min(max(lb, 0), PCELLS - 18);

    const int h = j >> 2;                  // d1-corner this lane holds
    float f10 = h ? wa[1] : 1.f - wa[1];
    float cA0 = (1.f - wa[0]) * ta * f10;  // d0 bottom
    float cB0 = wa[0] * ta * f10;          // d0+1
    float f11 = h ? wb[1] : 1.f - wb[1];
    float cA1 = (1.f - wb[0]) * tb * f11;
    float cB1 = wb[0] * tb * f11;

    // --- gathers ------------------------------------------------------------
    const char* gb = (const char*)gt;
    const size_t off = (size_t)16 * j;
    f32x4 vA0 = *(const f32x4*)(gb + (size_t)l0 * 64 + off);         // (l, l+1)
    f32x4 vB0 = *(const f32x4*)(gb + (size_t)(l0 + 16) * 64 + off);  // (l+16, l+17)
    f32x4 vA1 = *(const f32x4*)(gb + (size_t)l1 * 64 + off);
    f32x4 vB1 = *(const f32x4*)(gb + (size_t)(l1 + 16) * 64 + off);

    // --- accumulate ---------------------------------------------------------
    float acc0[8], acc1[8];
    const __half2* hA0 = (const __half2*)&vA0;
    const __half2* hB0 = (const __half2*)&vB0;
    const __half2* hA1 = (const __half2*)&vA1;
    const __half2* hB1 = (const __half2*)&vB1;
#pragma unroll
    for (int k = 0; k < 4; ++k) {
        float2 a0 = __half22float2(hA0[k]);
        float2 b0 = __half22float2(hB0[k]);
        acc0[2 * k]     = cA0 * a0.x + cB0 * b0.x;
        acc0[2 * k + 1] = cA0 * a0.y + cB0 * b0.y;
        float2 a1 = __half22float2(hA1[k]);
        float2 b1 = __half22float2(hB1[k]);
        acc1[2 * k]     = cA1 * a1.x + cB1 * b1.x;
        acc1[2 * k + 1] = cA1 * a1.y + cB1 * b1.y;
    }
    // combine the two d1 corners (lanes j and j^4 hold the same channel octet)
#pragma unroll
    for (int k = 0; k < 8; ++k) {
        acc0[k] += swz_xor4(acc0[k]);
        acc1[k] += swz_xor4(acc1[k]);
    }

    const int qo = j & 3;
    f32x4 lo0 = *(f32x4*)&acc0[0], hi0 = *(f32x4*)&acc0[4];
    f32x4 st0 = h ? hi0 : lo0;
    __builtin_nontemporal_store(
        st0, (f32x4*)(out + (size_t)n0 * CCH + 8 * qo + 4 * h));
    if (has1) {
        f32x4 lo1 = *(f32x4*)&acc1[0], hi1 = *(f32x4*)&acc1[4];
        f32x4 st1 = h ? hi1 : lo1;
        __builtin_nontemporal_store(
            st1, (f32x4*)(out + (size_t)n1 * CCH + 8 * qo + 4 * h));
    }
}

// ---------------------------------------------------------------------------
// Fallback: direct gather from native (C,P) f32 layout (workspace too small).
// ---------------------------------------------------------------------------
__device__ __forceinline__ void ray_corners_orig(
        const float* __restrict__ ray, const float* __restrict__ mn,
        const float* __restrict__ mx, int n, int* lin, float* wt) {
    float w[5]; int b[5];
#pragma unroll
    for (int d = 0; d < 5; ++d) {
        float m   = mn[d];
        float inv = __builtin_amdgcn_rcpf(mx[d] - m) * 15.0f;
        float i0  = (ray[(size_t)n * 5 + d] - m) * inv;
        float f0  = floorf(i0);
        b[d] = (int)f0;  w[d] = i0 - f0;
    }
    float tau = (1.f - w[2]) * (1.f - w[3]) * (1.f - w[4]);
    int rest  = b[2] * 256 + b[3] * 16 + b[4];
    wt[0] = (1.f - w[0]) * (1.f - w[1]) * tau;
    wt[1] = w[0] * (1.f - w[1]) * tau;
    wt[2] = (1.f - w[0]) * w[1] * tau;
    wt[3] = w[0] * w[1] * tau;
    int l00 = b[0] * 65536 + b[1] * 4096 + rest;
    int lv[4] = { l00, l00 + 65536, l00 + 4096, l00 + 65536 + 4096 };
#pragma unroll
    for (int f = 0; f < 4; ++f)
        lin[f] = min(max(lv[f], 0), PCELLS - 1);
}

__global__ __launch_bounds__(256) void direct_kernel(
        const float* __restrict__ ray, const float* __restrict__ g,
        const float* __restrict__ mn, const float* __restrict__ mx,
        float* __restrict__ out, int N) {
    int tid = blockIdx.x * blockDim.x + threadIdx.x;
    int n = tid >> 5;
    int c = tid & 31;
    if (n >= N) return;
    int lin[4]; float wt[4];
    ray_corners_orig(ray, mn, mx, n, lin, wt);
    const float* gc = g + (size_t)c * PCELLS;
    float acc = wt[0] * gc[lin[0]] + wt[1] * gc[lin[1]] +
                wt[2] * gc[lin[2]] + wt[3] * gc[lin[3]];
    out[(size_t)n * CCH + c] = acc;
}

extern "C" void kernel_launch(void* const* d_in, const int* in_sizes, int n_in,
                              void* d_out, int out_size, void* d_ws, size_t ws_size,
                              hipStream_t stream) {
    const float* ray  = (const float*)d_in[0];
    const float* grid = (const float*)d_in[1];
    const float* mn   = (const float*)d_in[2];
    const float* mx   = (const float*)d_in[3];
    float* out = (float*)d_out;
    const int N = in_sizes[0] / 5;

    const size_t gt_bytes = (size_t)PCELLS * CCH * sizeof(__half);   // 64 MiB

    if (ws_size >= gt_bytes) {
        __half* gt = (__half*)d_ws;
        transpose_kernel<<<PCELLS / 128, 256, 0, stream>>>(grid, gt);

        long long waves   = ((long long)N + 15) / 16;   // 16 rays per wave
        long long threads = waves * 64;
        fused_gather<<<(int)((threads + 255) / 256), 256, 0, stream>>>(
            ray, gt, mn, mx, out, N);
    } else {
        long long total = (long long)N * CCH;
        direct_kernel<<<(int)((total + 255) / 256), 256, 0, stream>>>(
            ray, grid, mn, mx, out, N);
    }
}